// Round 11
// baseline (2890.894 us; speedup 1.0000x reference)
//
#include <hip/hip_runtime.h>

#define B_ 256
#define T_ 512
#define I_ 256
#define H_ 256
#define CHUNK 64

typedef float    f32x4 __attribute__((ext_vector_type(4)));
typedef _Float16 f16x2 __attribute__((ext_vector_type(2)));
typedef _Float16 f16x8 __attribute__((ext_vector_type(8)));

static __device__ __forceinline__ f16x8 cvt8(f32x4 a, f32x4 b) {
  return f16x8{(_Float16)a[0], (_Float16)a[1], (_Float16)a[2], (_Float16)a[3],
               (_Float16)b[0], (_Float16)b[1], (_Float16)b[2], (_Float16)b[3]};
}

// ---------------- V0: fused RNN (verbatim 369/406us kernel, produces d_out) ----------------
__global__ __launch_bounds__(512) void rnn_fused(const float* __restrict__ x,
                                                 const float* __restrict__ wxf,
                                                 const float* __restrict__ whf,
                                                 const float* __restrict__ bias_g,
                                                 float* __restrict__ io) {
  __shared__ __align__(16) float    xps[CHUNK][H_];
  __shared__ __align__(16) float    outs[CHUNK][H_];
  __shared__ __align__(16) _Float16 hb[2][H_];

  const int tid = threadIdx.x;
  const int l   = tid & 63;
  const int w   = tid >> 6;
  const int lr  = l & 15;
  const int g   = l >> 4;
  const int h0  = w * 32;
  const size_t base = (size_t)blockIdx.x * (size_t)(T_ * H_);

  f16x8 wB[16];
  f16x8 xB[16];
#pragma unroll
  for (int tile = 0; tile < 2; ++tile) {
#pragma unroll
    for (int kc = 0; kc < 8; ++kc) {
      const float* ph = whf + (size_t)(h0 + tile * 16 + lr) * H_ + kc * 32 + g * 8;
      wB[tile * 8 + kc] = cvt8(*(const f32x4*)ph, *(const f32x4*)(ph + 4));
      const float* px = wxf + (size_t)(h0 + tile * 16 + lr) * I_ + kc * 32 + g * 8;
      xB[tile * 8 + kc] = cvt8(*(const f32x4*)px, *(const f32x4*)(px + 4));
    }
  }
  const float bias0 = bias_g[h0 + lr];
  const float bias1 = bias_g[h0 + 16 + lr];
  if (tid < 128) ((f16x2*)hb[0])[tid] = f16x2{(_Float16)0.f, (_Float16)0.f};

  int cur = 0;
  for (int t0 = 0; t0 < T_; t0 += CHUNK) {
#pragma unroll 1
    for (int tt = 0; tt < CHUNK / 16; ++tt) {
      f32x4 aE0 = {}, aO0 = {}, aE1 = {}, aO1 = {};
      const float* xrow = x + base + (size_t)(t0 + tt * 16 + lr) * I_;
#pragma unroll
      for (int kc = 0; kc < 8; kc += 2) {
        const f32x4* p0 = (const f32x4*)(xrow + kc * 32 + g * 8);
        f16x8 a0 = cvt8(p0[0], p0[1]);
        const f32x4* p1 = (const f32x4*)(xrow + (kc + 1) * 32 + g * 8);
        f16x8 a1 = cvt8(p1[0], p1[1]);
        aE0 = __builtin_amdgcn_mfma_f32_16x16x32_f16(a0, xB[kc],         aE0, 0, 0, 0);
        aE1 = __builtin_amdgcn_mfma_f32_16x16x32_f16(a0, xB[8 + kc],     aE1, 0, 0, 0);
        aO0 = __builtin_amdgcn_mfma_f32_16x16x32_f16(a1, xB[kc + 1],     aO0, 0, 0, 0);
        aO1 = __builtin_amdgcn_mfma_f32_16x16x32_f16(a1, xB[8 + kc + 1], aO1, 0, 0, 0);
      }
      f32x4 y0 = aE0 + aO0, y1 = aE1 + aO1;
#pragma unroll
      for (int r = 0; r < 4; ++r) {
        xps[tt * 16 + g * 4 + r][h0 + lr]      = y0[r] + bias0;
        xps[tt * 16 + g * 4 + r][h0 + 16 + lr] = y1[r] + bias1;
      }
    }
    __syncthreads();

#pragma unroll 1
    for (int s = 0; s < CHUNK; ++s) {
      const float xp0 = xps[s][h0 + lr];
      const float xp1 = xps[s][h0 + 16 + lr];
      f32x4 aE0 = {}, aO0 = {}, aE1 = {}, aO1 = {};
      const f16x8* hp = (const f16x8*)hb[cur];
#pragma unroll
      for (int kc = 0; kc < 8; kc += 2) {
        f16x8 hv0 = hp[kc * 4 + g];
        f16x8 hv1 = hp[(kc + 1) * 4 + g];
        aE0 = __builtin_amdgcn_mfma_f32_16x16x32_f16(hv0, wB[kc],         aE0, 0, 0, 0);
        aE1 = __builtin_amdgcn_mfma_f32_16x16x32_f16(hv0, wB[8 + kc],     aE1, 0, 0, 0);
        aO0 = __builtin_amdgcn_mfma_f32_16x16x32_f16(hv1, wB[kc + 1],     aO0, 0, 0, 0);
        aO1 = __builtin_amdgcn_mfma_f32_16x16x32_f16(hv1, wB[8 + kc + 1], aO1, 0, 0, 0);
      }
      float y0 = aE0[0] + aO0[0] + xp0;
      float y1 = aE1[0] + aO1[0] + xp1;
      float e0 = __expf(2.f * y0);
      float hv0s = 1.f - 2.f * __builtin_amdgcn_rcpf(1.f + e0);
      float e1 = __expf(2.f * y1);
      float hv1s = 1.f - 2.f * __builtin_amdgcn_rcpf(1.f + e1);
      if (l < 16) {
        outs[s][h0 + lr]      = hv0s;
        outs[s][h0 + 16 + lr] = hv1s;
        _Float16* hn = hb[cur ^ 1];
        hn[h0 + lr]      = (_Float16)hv0s;
        hn[h0 + 16 + lr] = (_Float16)hv1s;
      }
      __syncthreads();
      cur ^= 1;
    }

    {
      const f32x4* src = (const f32x4*)outs;
      f32x4* dst = (f32x4*)(io + base + (size_t)t0 * H_);
#pragma unroll
      for (int i = 0; i < (CHUNK * H_ / 4) / 512; ++i)
        dst[i * 512 + tid] = src[i * 512 + tid];
    }
    __syncthreads();
  }
}

// =============== ABLATION PROBES (2048 steps = 4x T each; write only d_ws) ===============
// Observability rule: a probe MISSING from the top-5 table ran faster than V0's
// ~406us => per-step < ~200cyc => the component it removed is the dominant cost.

// ---- probe A: phase 2 verbatim (ds_read h + MFMA + epilogue + barrier) ----
__global__ __launch_bounds__(512) void abl_p2(const float* __restrict__ whf,
                                              const float* __restrict__ bias_g,
                                              float* __restrict__ wsf) {
  __shared__ __align__(16) float    xps[CHUNK][H_];
  __shared__ __align__(16) float    outs[CHUNK][H_];
  __shared__ __align__(16) _Float16 hb[2][H_];
  const int tid = threadIdx.x;
  const int l   = tid & 63;
  const int w   = tid >> 6;
  const int lr  = l & 15;
  const int g   = l >> 4;
  const int h0  = w * 32;

  f16x8 wB[16];
#pragma unroll
  for (int tile = 0; tile < 2; ++tile)
#pragma unroll
    for (int kc = 0; kc < 8; ++kc) {
      const float* ph = whf + (size_t)(h0 + tile * 16 + lr) * H_ + kc * 32 + g * 8;
      wB[tile * 8 + kc] = cvt8(*(const f32x4*)ph, *(const f32x4*)(ph + 4));
    }
  const float bias0 = bias_g[h0 + lr];
  // zero LDS (deterministic, no NaNs)
#pragma unroll
  for (int i = 0; i < 32; ++i) ((float*)xps)[i * 512 + tid] = 0.f;
  if (tid < 128) ((f16x2*)hb[0])[tid] = f16x2{(_Float16)0.f, (_Float16)0.f};
  __syncthreads();

  int cur = 0;
#pragma unroll 1
  for (int s2 = 0; s2 < 2048; ++s2) {
    const int s = s2 & 63;
    const float xp0 = xps[s][h0 + lr] + bias0;
    const float xp1 = xps[s][h0 + 16 + lr];
    f32x4 aE0 = {}, aO0 = {}, aE1 = {}, aO1 = {};
    const f16x8* hp = (const f16x8*)hb[cur];
#pragma unroll
    for (int kc = 0; kc < 8; kc += 2) {
      f16x8 hv0 = hp[kc * 4 + g];
      f16x8 hv1 = hp[(kc + 1) * 4 + g];
      aE0 = __builtin_amdgcn_mfma_f32_16x16x32_f16(hv0, wB[kc],         aE0, 0, 0, 0);
      aE1 = __builtin_amdgcn_mfma_f32_16x16x32_f16(hv0, wB[8 + kc],     aE1, 0, 0, 0);
      aO0 = __builtin_amdgcn_mfma_f32_16x16x32_f16(hv1, wB[kc + 1],     aO0, 0, 0, 0);
      aO1 = __builtin_amdgcn_mfma_f32_16x16x32_f16(hv1, wB[8 + kc + 1], aO1, 0, 0, 0);
    }
    float y0 = aE0[0] + aO0[0] + xp0;
    float y1 = aE1[0] + aO1[0] + xp1;
    float e0 = __expf(2.f * y0);
    float h0s = 1.f - 2.f * __builtin_amdgcn_rcpf(1.f + e0);
    float e1 = __expf(2.f * y1);
    float h1s = 1.f - 2.f * __builtin_amdgcn_rcpf(1.f + e1);
    if (l < 16) {
      outs[s][h0 + lr]      = h0s;
      outs[s][h0 + 16 + lr] = h1s;
      _Float16* hn = hb[cur ^ 1];
      hn[h0 + lr]      = (_Float16)h0s;
      hn[h0 + 16 + lr] = (_Float16)h1s;
    }
    __syncthreads();
    cur ^= 1;
  }
  wsf[(blockIdx.x * 512 + tid) & 32767] = outs[0][tid & 255] + (float)hb[0][tid & 255];
}

// ---- probe B: h from REGISTERS (ds_reads of h removed; chain + hoist-proofing kept) ----
// Each step injects the step's tanh result into EVERY fragment -> all 16 MFMAs carry a
// cross-step serial dependency and cannot be hoisted (fixes round-9's confound).
__global__ __launch_bounds__(512) void abl_reg(const float* __restrict__ whf,
                                               const float* __restrict__ bias_g,
                                               float* __restrict__ wsf) {
  __shared__ __align__(16) float    xps[CHUNK][H_];
  __shared__ __align__(16) float    outs[CHUNK][H_];
  __shared__ __align__(16) _Float16 hb[2][H_];
  const int tid = threadIdx.x;
  const int l   = tid & 63;
  const int w   = tid >> 6;
  const int lr  = l & 15;
  const int g   = l >> 4;
  const int h0  = w * 32;

  f16x8 wB[16];
#pragma unroll
  for (int tile = 0; tile < 2; ++tile)
#pragma unroll
    for (int kc = 0; kc < 8; ++kc) {
      const float* ph = whf + (size_t)(h0 + tile * 16 + lr) * H_ + kc * 32 + g * 8;
      wB[tile * 8 + kc] = cvt8(*(const f32x4*)ph, *(const f32x4*)(ph + 4));
    }
  const float bias0 = bias_g[h0 + lr];
#pragma unroll
  for (int i = 0; i < 32; ++i) ((float*)xps)[i * 512 + tid] = 0.f;
  if (tid < 128) ((f16x2*)hb[0])[tid] = f16x2{(_Float16)0.f, (_Float16)0.f};
  __syncthreads();

  f16x8 hc[8];
  const f16x8* hp0 = (const f16x8*)hb[0];
#pragma unroll
  for (int kc = 0; kc < 8; ++kc) hc[kc] = hp0[kc * 4 + g];

  int cur = 0;
#pragma unroll 1
  for (int s2 = 0; s2 < 2048; ++s2) {
    const int s = s2 & 63;
    const float xp0 = xps[s][h0 + lr] + bias0;
    const float xp1 = xps[s][h0 + 16 + lr];
    f32x4 aE0 = {}, aO0 = {}, aE1 = {}, aO1 = {};
#pragma unroll
    for (int kc = 0; kc < 8; kc += 2) {
      aE0 = __builtin_amdgcn_mfma_f32_16x16x32_f16(hc[kc],     wB[kc],         aE0, 0, 0, 0);
      aE1 = __builtin_amdgcn_mfma_f32_16x16x32_f16(hc[kc],     wB[8 + kc],     aE1, 0, 0, 0);
      aO0 = __builtin_amdgcn_mfma_f32_16x16x32_f16(hc[kc + 1], wB[kc + 1],     aO0, 0, 0, 0);
      aO1 = __builtin_amdgcn_mfma_f32_16x16x32_f16(hc[kc + 1], wB[8 + kc + 1], aO1, 0, 0, 0);
    }
    float y0 = aE0[0] + aO0[0] + xp0;
    float y1 = aE1[0] + aO1[0] + xp1;
    float e0 = __expf(2.f * y0);
    float h0s = 1.f - 2.f * __builtin_amdgcn_rcpf(1.f + e0);
    float e1 = __expf(2.f * y1);
    float h1s = 1.f - 2.f * __builtin_amdgcn_rcpf(1.f + e1);
#pragma unroll
    for (int kc = 0; kc < 8; ++kc) hc[kc][0] = (_Float16)h0s;   // serial chain into every frag
    if (l < 16) {
      outs[s][h0 + lr]      = h0s;
      outs[s][h0 + 16 + lr] = h1s;
      _Float16* hn = hb[cur ^ 1];
      hn[h0 + lr]      = (_Float16)h0s;
      hn[h0 + 16 + lr] = (_Float16)h1s;
    }
    __syncthreads();
    cur ^= 1;
  }
  wsf[(blockIdx.x * 512 + tid) & 32767] = outs[0][tid & 255] + (float)hb[0][tid & 255] + (float)hc[0][0];
}

// ---- probe C: MFMAs removed (ds_reads + epilogue + writes + barrier + chain kept) ----
__global__ __launch_bounds__(512) void abl_nomfma(const float* __restrict__ bias_g,
                                                  float* __restrict__ wsf) {
  __shared__ __align__(16) float    xps[CHUNK][H_];
  __shared__ __align__(16) float    outs[CHUNK][H_];
  __shared__ __align__(16) _Float16 hb[2][H_];
  const int tid = threadIdx.x;
  const int l   = tid & 63;
  const int w   = tid >> 6;
  const int lr  = l & 15;
  const int g   = l >> 4;
  const int h0  = w * 32;
  const float bias0 = bias_g[h0 + lr];
#pragma unroll
  for (int i = 0; i < 32; ++i) ((float*)xps)[i * 512 + tid] = 0.f;
  if (tid < 128) ((f16x2*)hb[0])[tid] = f16x2{(_Float16)0.f, (_Float16)0.f};
  __syncthreads();

  int cur = 0;
#pragma unroll 1
  for (int s2 = 0; s2 < 2048; ++s2) {
    const int s = s2 & 63;
    const float xp0 = xps[s][h0 + lr] + bias0;
    const float xp1 = xps[s][h0 + 16 + lr];
    const f16x8* hp = (const f16x8*)hb[cur];
    float acc0 = xp0, acc1 = xp1;
#pragma unroll
    for (int kc = 0; kc < 8; ++kc) {
      f16x8 hv = hp[kc * 4 + g];                      // same 8 broadcast ds_read_b128
      acc0 += (float)hv[0];                           // keep reads live (cheap VALU)
      acc1 += (float)hv[4];
    }
    float e0 = __expf(2.f * acc0);
    float h0s = 1.f - 2.f * __builtin_amdgcn_rcpf(1.f + e0);
    float e1 = __expf(2.f * acc1);
    float h1s = 1.f - 2.f * __builtin_amdgcn_rcpf(1.f + e1);
    if (l < 16) {
      outs[s][h0 + lr]      = h0s;
      outs[s][h0 + 16 + lr] = h1s;
      _Float16* hn = hb[cur ^ 1];
      hn[h0 + lr]      = (_Float16)h0s;
      hn[h0 + 16 + lr] = (_Float16)h1s;
    }
    __syncthreads();
    cur ^= 1;
  }
  wsf[(blockIdx.x * 512 + tid) & 32767] = outs[0][tid & 255] + (float)hb[0][tid & 255];
}

extern "C" void kernel_launch(void* const* d_in, const int* in_sizes, int n_in,
                              void* d_out, int out_size, void* d_ws, size_t ws_size,
                              hipStream_t stream) {
  const float* x  = (const float*)d_in[0];
  const float* wx = (const float*)d_in[1];
  const float* wh = (const float*)d_in[2];
  const float* b  = (const float*)d_in[3];
  float* out = (float*)d_out;

  rnn_fused<<<B_, 512, 0, stream>>>(x, wx, wh, b, out);

  if (ws_size >= 131072) {
    float* wsf = (float*)d_ws;
    abl_p2<<<B_, 512, 0, stream>>>(wh, b, wsf);
    abl_reg<<<B_, 512, 0, stream>>>(wh, b, wsf);
    abl_nomfma<<<B_, 512, 0, stream>>>(b, wsf);
  }
}

// Round 12
// 370.025 us; speedup vs baseline: 7.8127x; 7.8127x over previous
//
#include <hip/hip_runtime.h>

#define B_ 256
#define T_ 512
#define I_ 256
#define H_ 256
#define CHUNK 64

typedef float    f32x4 __attribute__((ext_vector_type(4)));
typedef _Float16 f16x2 __attribute__((ext_vector_type(2)));
typedef _Float16 f16x8 __attribute__((ext_vector_type(8)));

static __device__ __forceinline__ f16x8 cvt8(f32x4 a, f32x4 b) {
  return f16x8{(_Float16)a[0], (_Float16)a[1], (_Float16)a[2], (_Float16)a[3],
               (_Float16)b[0], (_Float16)b[1], (_Float16)b[2], (_Float16)b[3]};
}

// ---------------- fused RNN v9: phase-2 MFMA chains broken (16 independent accs) ----------------
// Ablation (r11): phase-2 = 1134 cyc/step; ds_reads of h are FREE (abl_reg == abl_p2);
// skeleton (epilogue+barrier+LDS writes) ~250 cyc; => ~880 cyc is the MFMA block.
// 32 MFMA/SIMD/step at ~27 cyc effective vs 4.85 µbench => dependency-stalled: V0 used
// four 4-deep serial C-operand chains. Fix: 16 independent MFMAs, each C=0, one per
// (tile, k-slice); only element [0] of each D is real (broadcast-A trick) -> reduce
// with two 7-add trees. Chain depth 4 -> 1, per-wave MFMA ILP 4 -> 16.
__global__ __launch_bounds__(512) void rnn_fused(const float* __restrict__ x,
                                                 const float* __restrict__ wxf,
                                                 const float* __restrict__ whf,
                                                 const float* __restrict__ bias_g,
                                                 float* __restrict__ io) {
  __shared__ __align__(16) float    xps[CHUNK][H_];
  __shared__ __align__(16) float    outs[CHUNK][H_];
  __shared__ __align__(16) _Float16 hb[2][H_];

  const int tid = threadIdx.x;
  const int l   = tid & 63;
  const int w   = tid >> 6;
  const int lr  = l & 15;
  const int g   = l >> 4;
  const int h0  = w * 32;
  const size_t base = (size_t)blockIdx.x * (size_t)(T_ * H_);

  f16x8 wB[16];
  f16x8 xB[16];
#pragma unroll
  for (int tile = 0; tile < 2; ++tile) {
#pragma unroll
    for (int kc = 0; kc < 8; ++kc) {
      const float* ph = whf + (size_t)(h0 + tile * 16 + lr) * H_ + kc * 32 + g * 8;
      wB[tile * 8 + kc] = cvt8(*(const f32x4*)ph, *(const f32x4*)(ph + 4));
      const float* px = wxf + (size_t)(h0 + tile * 16 + lr) * I_ + kc * 32 + g * 8;
      xB[tile * 8 + kc] = cvt8(*(const f32x4*)px, *(const f32x4*)(px + 4));
    }
  }
  const float bias0 = bias_g[h0 + lr];
  const float bias1 = bias_g[h0 + 16 + lr];
  if (tid < 128) ((f16x2*)hb[0])[tid] = f16x2{(_Float16)0.f, (_Float16)0.f};

  const f32x4 z4 = f32x4{0.f, 0.f, 0.f, 0.f};

  int cur = 0;
  for (int t0 = 0; t0 < T_; t0 += CHUNK) {
    // ---- phase 1: xp chunk from global x (unchanged) ----
#pragma unroll 1
    for (int tt = 0; tt < CHUNK / 16; ++tt) {
      f32x4 aE0 = {}, aO0 = {}, aE1 = {}, aO1 = {};
      const float* xrow = x + base + (size_t)(t0 + tt * 16 + lr) * I_;
#pragma unroll
      for (int kc = 0; kc < 8; kc += 2) {
        const f32x4* p0 = (const f32x4*)(xrow + kc * 32 + g * 8);
        f16x8 a0 = cvt8(p0[0], p0[1]);
        const f32x4* p1 = (const f32x4*)(xrow + (kc + 1) * 32 + g * 8);
        f16x8 a1 = cvt8(p1[0], p1[1]);
        aE0 = __builtin_amdgcn_mfma_f32_16x16x32_f16(a0, xB[kc],         aE0, 0, 0, 0);
        aE1 = __builtin_amdgcn_mfma_f32_16x16x32_f16(a0, xB[8 + kc],     aE1, 0, 0, 0);
        aO0 = __builtin_amdgcn_mfma_f32_16x16x32_f16(a1, xB[kc + 1],     aO0, 0, 0, 0);
        aO1 = __builtin_amdgcn_mfma_f32_16x16x32_f16(a1, xB[8 + kc + 1], aO1, 0, 0, 0);
      }
      f32x4 y0 = aE0 + aO0, y1 = aE1 + aO1;
#pragma unroll
      for (int r = 0; r < 4; ++r) {
        xps[tt * 16 + g * 4 + r][h0 + lr]      = y0[r] + bias0;
        xps[tt * 16 + g * 4 + r][h0 + 16 + lr] = y1[r] + bias1;
      }
    }
    __syncthreads();

    // ---- phase 2: 64 recurrence steps; 16 INDEPENDENT MFMAs per wave-step ----
#pragma unroll 1
    for (int s = 0; s < CHUNK; ++s) {
      const float xp0 = xps[s][h0 + lr];
      const float xp1 = xps[s][h0 + 16 + lr];
      const f16x8* hp = (const f16x8*)hb[cur];

      f32x4 a0[8], a1[8];                             // tile0 / tile1, one acc per k-slice
#pragma unroll
      for (int kc = 0; kc < 8; ++kc) {
        f16x8 hv = hp[kc * 4 + g];                    // broadcast b128 (measured free)
        a0[kc] = __builtin_amdgcn_mfma_f32_16x16x32_f16(hv, wB[kc],     z4, 0, 0, 0);
        a1[kc] = __builtin_amdgcn_mfma_f32_16x16x32_f16(hv, wB[8 + kc], z4, 0, 0, 0);
      }
      // reduce element [0] of the 8 accs per tile (3-deep trees)
      float y0 = ((a0[0][0] + a0[1][0]) + (a0[2][0] + a0[3][0])) +
                 ((a0[4][0] + a0[5][0]) + (a0[6][0] + a0[7][0])) + xp0;
      float y1 = ((a1[0][0] + a1[1][0]) + (a1[2][0] + a1[3][0])) +
                 ((a1[4][0] + a1[5][0]) + (a1[6][0] + a1[7][0])) + xp1;
      float e0 = __expf(2.f * y0);
      float hv0s = 1.f - 2.f * __builtin_amdgcn_rcpf(1.f + e0);   // tanh
      float e1 = __expf(2.f * y1);
      float hv1s = 1.f - 2.f * __builtin_amdgcn_rcpf(1.f + e1);
      if (l < 16) {
        outs[s][h0 + lr]      = hv0s;
        outs[s][h0 + 16 + lr] = hv1s;
        _Float16* hn = hb[cur ^ 1];
        hn[h0 + lr]      = (_Float16)hv0s;
        hn[h0 + 16 + lr] = (_Float16)hv1s;
      }
      __syncthreads();
      cur ^= 1;
    }

    // ---- phase 3: bulk flush outs -> global (unchanged) ----
    {
      const f32x4* src = (const f32x4*)outs;
      f32x4* dst = (f32x4*)(io + base + (size_t)t0 * H_);
#pragma unroll
      for (int i = 0; i < (CHUNK * H_ / 4) / 512; ++i)
        dst[i * 512 + tid] = src[i * 512 + tid];
    }
    __syncthreads();
  }
}

extern "C" void kernel_launch(void* const* d_in, const int* in_sizes, int n_in,
                              void* d_out, int out_size, void* d_ws, size_t ws_size,
                              hipStream_t stream) {
  const float* x  = (const float*)d_in[0];
  const float* wx = (const float*)d_in[1];
  const float* wh = (const float*)d_in[2];
  const float* b  = (const float*)d_in[3];
  float* out = (float*)d_out;
  (void)d_ws; (void)ws_size;
  rnn_fused<<<B_, 512, 0, stream>>>(x, wx, wh, b, out);
}